// Round 2
// baseline (597.017 us; speedup 1.0000x reference)
//
#include <hip/hip_runtime.h>
#include <hip/hip_bf16.h>

// Problem constants (B=2, S=2048, D=1536, H=12, hd=128)
#define S_LEN   2048
#define DMODEL  1536
#define NBATCH  2
#define NHEADS  12
#define MROWS   (NBATCH * S_LEN)        // 4096
#define NCHUNK  16
#define CHUNK   128                     // S_LEN / NCHUNK

typedef unsigned short u16;
typedef __attribute__((ext_vector_type(8))) short bf16x8;   // 8 bf16 = 4 VGPRs
typedef __attribute__((ext_vector_type(4))) float f32x4;

// round-to-nearest-even fp32 -> bf16
__device__ __forceinline__ u16 f2bf(float x) {
  unsigned u = __float_as_uint(x);
  u += 0x7fffu + ((u >> 16) & 1u);
  return (u16)(u >> 16);
}

// ---------------------------------------------------------------- fused cvt fp32->bf16 (3 tensors)
#define N4_HID  1572864     // 2*2048*1536/4
#define N4_W    589824      // 1536*1536/4
__global__ void cvt_all(const float4* __restrict__ h, const float4* __restrict__ wf,
                        const float4* __restrict__ wp, ushort4* __restrict__ ho,
                        ushort4* __restrict__ wfo, ushort4* __restrict__ wpo) {
  int t = blockIdx.x * blockDim.x + threadIdx.x;   // N4_HID + 2*N4_W = 2752512
  const float4* src;
  ushort4* dst;
  int idx;
  if (t < N4_HID)            { src = h;  dst = ho;  idx = t; }
  else if (t < N4_HID + N4_W){ src = wf; dst = wfo; idx = t - N4_HID; }
  else                       { src = wp; dst = wpo; idx = t - N4_HID - N4_W; }
  float4 f = src[idx];
  ushort4 o;
  o.x = f2bf(f.x); o.y = f2bf(f.y); o.z = f2bf(f.z); o.w = f2bf(f.w);
  dst[idx] = o;
}

// ---------------------------------------------------------------- bf16 GEMM  C = A @ B^T + bias
// m97 structure: 128x128 tile, BK=32, 4 waves (2x2 of 64x64), 16x16x32 MFMA,
// global_load_lds width=16 staging. Optionally emits per-column sums of the
// 128-row tile (the scan chunk sums) from the AGPRs — no extra global reads.
__device__ __forceinline__ void gld_lds16(u16* lds, const u16* g) {
  __builtin_amdgcn_global_load_lds(
      (const __attribute__((address_space(1))) unsigned int*)g,
      (__attribute__((address_space(3))) unsigned int*)lds, 16, 0, 0);
}

template <bool WITH_CSUM>
__global__ __launch_bounds__(256)
void gemm_bt_bias(const u16* __restrict__ A, const u16* __restrict__ B,
                  const float* __restrict__ bias, float* __restrict__ C,
                  float* __restrict__ cs, int Ndim, int Kdim) {
  __shared__ __align__(16) u16 As[128 * 32];   // row-major, row stride 32 bf16 (64 B)
  __shared__ __align__(16) u16 Bs[128 * 32];
  __shared__ float colpart[2][128];            // cross-wave column-sum combine

  const int tid  = threadIdx.x;
  const int wave = tid >> 6;
  const int lane = tid & 63;
  const int l15  = lane & 15;
  const int quad = lane >> 4;
  const int bm = blockIdx.y * 128;
  const int bn = blockIdx.x * 128;
  const int wm = (wave >> 1) * 64;
  const int wn = (wave & 1) * 64;

  f32x4 acc[4][4] = {};

  const int srow = wave * 32 + (lane >> 2);
  const int skk  = (lane & 3) * 8;
  const u16* gA = A + (size_t)(bm + srow) * Kdim + skk;
  const u16* gB = B + (size_t)(bn + srow) * Kdim + skk;
  u16* lA = &As[(wave * 32) * 32];
  u16* lB = &Bs[(wave * 32) * 32];
  const size_t rstep16 = (size_t)16 * Kdim;

  for (int k0 = 0; k0 < Kdim; k0 += 32) {
    gld_lds16(lA,           gA + k0);
    gld_lds16(lA + 16 * 32, gA + k0 + rstep16);
    gld_lds16(lB,           gB + k0);
    gld_lds16(lB + 16 * 32, gB + k0 + rstep16);
    __syncthreads();

    bf16x8 af[4], bfr[4];
#pragma unroll
    for (int i = 0; i < 4; ++i)
      af[i] = *(const bf16x8*)&As[(wm + i * 16 + l15) * 32 + quad * 8];
#pragma unroll
    for (int j = 0; j < 4; ++j)
      bfr[j] = *(const bf16x8*)&Bs[(wn + j * 16 + l15) * 32 + quad * 8];
#pragma unroll
    for (int i = 0; i < 4; ++i)
#pragma unroll
      for (int j = 0; j < 4; ++j)
        acc[i][j] = __builtin_amdgcn_mfma_f32_16x16x32_bf16(af[i], bfr[j], acc[i][j], 0, 0, 0);
    __syncthreads();
  }

  // epilogue: C/D layout col = lane&15, row = quad*4 + reg   [verified m89/m91]
  const int r0 = quad * 4;
#pragma unroll
  for (int j = 0; j < 4; ++j) {
    const int col = bn + wn + j * 16 + l15;
    const float bj = bias[col];
    float s = 0.f;
#pragma unroll
    for (int i = 0; i < 4; ++i) {
      const int row = bm + wm + i * 16 + r0;
#pragma unroll
      for (int r = 0; r < 4; ++r) {
        float cv = acc[i][j][r] + bj;
        C[(size_t)(row + r) * Ndim + col] = cv;
        s += cv;
      }
    }
    if (WITH_CSUM) {
      // sum the wave's 64 rows for this column: reduce across quad groups
      s += __shfl_xor(s, 16);
      s += __shfl_xor(s, 32);
      if (quad == 0) colpart[wm >> 6][wn + j * 16 + l15] = s;
    }
  }
  if (WITH_CSUM) {
    __syncthreads();
    if (tid < 128) {
      const int b = bm >> 11;                 // 2048 rows per batch
      const int c = (bm & 2047) >> 7;         // 128-row chunk within batch
      cs[((size_t)b * NCHUNK + c) * DMODEL + bn + tid] =
          colpart[0][tid] + colpart[1][tid];
    }
  }
}

// ---------------------------------------------------------------- fused scan + windowed average
// One thread per (b, chunk, d): reconstructs lead = P[i] and trail = P[i-w]
// from chunk sums + short pre-walk, emits bf16 window averages directly.
// No prefix array is ever materialized. All branches wave-uniform
// (64 consecutive d share one head; chunk boundaries 1536-aligned).
__global__ void winavg_fused(const float* __restrict__ v, const float* __restrict__ cs,
                             u16* __restrict__ A2) {
  int t = blockIdx.x * blockDim.x + threadIdx.x;   // NBATCH*NCHUNK*DMODEL
  int d = t % DMODEL;
  int c = (t / DMODEL) % NCHUNK;
  int b = t / (DMODEL * NCHUNK);
  const int h = d >> 7;
  const int w = (2 << h) - 1;                      // 2^(h+1)-1
  const float* vb = v + (size_t)b * S_LEN * DMODEL + d;     // row i at vb[i*DMODEL]
  const float* csb = cs + (size_t)b * NCHUNK * DMODEL + d;  // chunk cc at csb[cc*DMODEL]

  // lead = P[i0-1]
  const int i0 = c * CHUNK;
  float lead = 0.f;
  for (int cc = 0; cc < c; ++cc) lead += csb[(size_t)cc * DMODEL];

  // trail = P[i0-w-1]  (0 if window start precedes the sequence)
  float trail = 0.f;
  const int tstart = i0 - w;
  if (tstart > 0) {
    const int tc = tstart >> 7;                    // whole chunks before tstart
    for (int cc = 0; cc < tc; ++cc) trail += csb[(size_t)cc * DMODEL];
#pragma unroll 4
    for (int r = tc * CHUNK; r < tstart; ++r) trail += vb[(size_t)r * DMODEL];
  }

  u16* out = A2 + ((size_t)(b * S_LEN + i0)) * DMODEL + d;
#pragma unroll 4
  for (int r = 0; r < CHUNK; ++r) {
    const int i = i0 + r;
    lead += vb[(size_t)i * DMODEL];
    float o;
    if (i < w) {                                   // window not yet full
      o = lead / (float)(i + 1);
    } else {
      trail += vb[(size_t)(i - w) * DMODEL];
      o = (lead - trail) / (float)w;
    }
    out[(size_t)r * DMODEL] = f2bf(o);
  }
}

// ---------------------------------------------------------------- analytic attn_weights [B,H,S,S]
__global__ void attn_weights_kernel(float4* __restrict__ out4) {
  int t = blockIdx.x * blockDim.x + threadIdx.x;   // B*H*S*S/4
  int j0 = (t & 511) << 2;
  int i  = (t >> 9) & (S_LEN - 1);
  int bh = t >> 20;                                // S*S/4 = 2^20
  int h  = bh >= NHEADS ? bh - NHEADS : bh;
  int w  = (2 << h) - 1;
  int len = min(i + 1, w);
  float inv = 1.0f / (float)len;
  int lo = i - w + 1;
  float4 r;
  r.x = (j0     <= i && j0     >= lo) ? inv : 0.f;
  r.y = (j0 + 1 <= i && j0 + 1 >= lo) ? inv : 0.f;
  r.z = (j0 + 2 <= i && j0 + 2 >= lo) ? inv : 0.f;
  r.w = (j0 + 3 <= i && j0 + 3 >= lo) ? inv : 0.f;
  out4[t] = r;
}

// ---------------------------------------------------------------- launch
extern "C" void kernel_launch(void* const* d_in, const int* in_sizes, int n_in,
                              void* d_out, int out_size, void* d_ws, size_t ws_size,
                              hipStream_t stream) {
  const float* hidden = (const float*)d_in[0];
  const float* W_fc   = (const float*)d_in[1];
  const float* b_fc   = (const float*)d_in[2];
  const float* W_proj = (const float*)d_in[3];
  const float* b_proj = (const float*)d_in[4];
  float* outp = (float*)d_out;

  // workspace layout (bytes):
  //   0        : A16   (12,582,912)  hidden bf16, later reused as winavg-output bf16
  //   12582912 : Wfc16 ( 4,718,592)
  //   17301504 : Wpj16 ( 4,718,592)
  //   22020096 : vbuf  (25,165,824)  fp32 v (never scanned in place now)
  //   47185920 : csums (   196,608)
  char* ws = (char*)d_ws;
  u16*   A16   = (u16*)(ws);
  u16*   Wfc16 = (u16*)(ws + 12582912);
  u16*   Wpj16 = (u16*)(ws + 17301504);
  float* vbuf  = (float*)(ws + 22020096);
  float* csums = (float*)(ws + 47185920);

  // 1) all fp32->bf16 conversions in one launch
  cvt_all<<<10752, 256, 0, stream>>>((const float4*)hidden, (const float4*)W_fc,
                                     (const float4*)W_proj, (ushort4*)A16,
                                     (ushort4*)Wfc16, (ushort4*)Wpj16);

  // 2) GEMM1: v = hidden @ W_fc^T + b_fc, with fused per-chunk column sums
  gemm_bt_bias<true><<<dim3(DMODEL / 128, MROWS / 128), 256, 0, stream>>>(
      A16, Wfc16, b_fc, vbuf, csums, DMODEL, DMODEL);

  // 3) fused scan + windowed average -> bf16 (reuse A16 buffer)
  winavg_fused<<<(NBATCH * NCHUNK * DMODEL) / 256, 256, 0, stream>>>(vbuf, csums, A16);

  // 4) GEMM2: out = winavg @ W_proj^T + b_proj -> d_out[0 : B*S*D]
  gemm_bt_bias<false><<<dim3(DMODEL / 128, MROWS / 128), 256, 0, stream>>>(
      A16, Wpj16, b_proj, outp, nullptr, DMODEL, DMODEL);

  // 5) attn_weights -> d_out[B*S*D : ...]
  attn_weights_kernel<<<(NBATCH * NHEADS * S_LEN * S_LEN / 4) / 256, 256, 0, stream>>>(
      (float4*)(outp + (size_t)MROWS * DMODEL));
}

// Round 3
// 567.876 us; speedup vs baseline: 1.0513x; 1.0513x over previous
//
#include <hip/hip_runtime.h>
#include <hip/hip_bf16.h>

// Problem constants (B=2, S=2048, D=1536, H=12, hd=128)
#define S_LEN   2048
#define DMODEL  1536
#define NBATCH  2
#define NHEADS  12
#define MROWS   (NBATCH * S_LEN)        // 4096
#define NCHUNK  64                      // scan chunks per sequence
#define CHUNK   32                      // S_LEN / NCHUNK

typedef unsigned short u16;
typedef __attribute__((ext_vector_type(8))) short bf16x8;   // 8 bf16 = 4 VGPRs
typedef __attribute__((ext_vector_type(4))) float f32x4;

// round-to-nearest-even fp32 -> bf16
__device__ __forceinline__ u16 f2bf(float x) {
  unsigned u = __float_as_uint(x);
  u += 0x7fffu + ((u >> 16) & 1u);
  return (u16)(u >> 16);
}
__device__ __forceinline__ float bf2f(u16 x) {
  return __uint_as_float(((unsigned)x) << 16);
}

// ---------------------------------------------------------------- fused cvt fp32->bf16 (3 tensors)
#define N4_HID  1572864     // 2*2048*1536/4
#define N4_W    589824      // 1536*1536/4
__global__ void cvt_all(const float4* __restrict__ h, const float4* __restrict__ wf,
                        const float4* __restrict__ wp, ushort4* __restrict__ ho,
                        ushort4* __restrict__ wfo, ushort4* __restrict__ wpo) {
  int t = blockIdx.x * blockDim.x + threadIdx.x;   // N4_HID + 2*N4_W = 2752512
  const float4* src;
  ushort4* dst;
  int idx;
  if (t < N4_HID)            { src = h;  dst = ho;  idx = t; }
  else if (t < N4_HID + N4_W){ src = wf; dst = wfo; idx = t - N4_HID; }
  else                       { src = wp; dst = wpo; idx = t - N4_HID - N4_W; }
  float4 f = src[idx];
  ushort4 o;
  o.x = f2bf(f.x); o.y = f2bf(f.y); o.z = f2bf(f.z); o.w = f2bf(f.w);
  dst[idx] = o;
}

// ---------------------------------------------------------------- bf16 GEMM  C = A @ B^T + bias
// m97 structure: 128x128 tile, BK=32, 4 waves (2x2 of 64x64), 16x16x32 MFMA,
// global_load_lds width=16 staging. Output type templated (fp32 or bf16).
// WITH_CSUM additionally emits per-column sums over each 32-row group of the
// tile (the scan chunk sums) straight from the accumulators — no extra reads.
__device__ __forceinline__ void gld_lds16(u16* lds, const u16* g) {
  __builtin_amdgcn_global_load_lds(
      (const __attribute__((address_space(1))) unsigned int*)g,
      (__attribute__((address_space(3))) unsigned int*)lds, 16, 0, 0);
}

template <bool WITH_CSUM, typename CT>
__global__ __launch_bounds__(256)
void gemm_bt_bias(const u16* __restrict__ A, const u16* __restrict__ B,
                  const float* __restrict__ bias, CT* __restrict__ C,
                  float* __restrict__ cs, int Ndim, int Kdim) {
  __shared__ __align__(16) u16 As[128 * 32];   // row-major, row stride 32 bf16 (64 B)
  __shared__ __align__(16) u16 Bs[128 * 32];
  __shared__ float colpart[4][128];            // 32-row-group column sums

  const int tid  = threadIdx.x;
  const int wave = tid >> 6;
  const int lane = tid & 63;
  const int l15  = lane & 15;
  const int quad = lane >> 4;
  const int bm = blockIdx.y * 128;
  const int bn = blockIdx.x * 128;
  const int wm = (wave >> 1) * 64;
  const int wn = (wave & 1) * 64;

  f32x4 acc[4][4] = {};

  const int srow = wave * 32 + (lane >> 2);
  const int skk  = (lane & 3) * 8;
  const u16* gA = A + (size_t)(bm + srow) * Kdim + skk;
  const u16* gB = B + (size_t)(bn + srow) * Kdim + skk;
  u16* lA = &As[(wave * 32) * 32];
  u16* lB = &Bs[(wave * 32) * 32];
  const size_t rstep16 = (size_t)16 * Kdim;

  for (int k0 = 0; k0 < Kdim; k0 += 32) {
    gld_lds16(lA,           gA + k0);
    gld_lds16(lA + 16 * 32, gA + k0 + rstep16);
    gld_lds16(lB,           gB + k0);
    gld_lds16(lB + 16 * 32, gB + k0 + rstep16);
    __syncthreads();

    bf16x8 af[4], bfr[4];
#pragma unroll
    for (int i = 0; i < 4; ++i)
      af[i] = *(const bf16x8*)&As[(wm + i * 16 + l15) * 32 + quad * 8];
#pragma unroll
    for (int j = 0; j < 4; ++j)
      bfr[j] = *(const bf16x8*)&Bs[(wn + j * 16 + l15) * 32 + quad * 8];
#pragma unroll
    for (int i = 0; i < 4; ++i)
#pragma unroll
      for (int j = 0; j < 4; ++j)
        acc[i][j] = __builtin_amdgcn_mfma_f32_16x16x32_bf16(af[i], bfr[j], acc[i][j], 0, 0, 0);
    __syncthreads();
  }

  // epilogue: C/D layout col = lane&15, row = quad*4 + reg   [verified m89/m91]
  const int r0 = quad * 4;
#pragma unroll
  for (int j = 0; j < 4; ++j) {
    const int col = bn + wn + j * 16 + l15;
    const float bj = bias[col];
    float sA = 0.f, sB = 0.f;     // rows [wm, wm+32) and [wm+32, wm+64)
#pragma unroll
    for (int i = 0; i < 4; ++i) {
      const int row = bm + wm + i * 16 + r0;
#pragma unroll
      for (int r = 0; r < 4; ++r) {
        float cv = acc[i][j][r] + bj;
        if constexpr (sizeof(CT) == 2)
          C[(size_t)(row + r) * Ndim + col] = (CT)f2bf(cv);
        else
          C[(size_t)(row + r) * Ndim + col] = (CT)cv;
        if (WITH_CSUM) { if (i < 2) sA += cv; else sB += cv; }
      }
    }
    if (WITH_CSUM) {
      sA += __shfl_xor(sA, 16); sA += __shfl_xor(sA, 32);
      sB += __shfl_xor(sB, 16); sB += __shfl_xor(sB, 32);
      if (quad == 0) {
        colpart[(wm >> 5) | 0][wn + j * 16 + l15] = sA;
        colpart[(wm >> 5) | 1][wn + j * 16 + l15] = sB;
      }
    }
  }
  if (WITH_CSUM) {
    __syncthreads();
    if (tid < 128) {
      const int b  = bm >> 11;               // 2048 rows per batch
      const int c0 = (bm & 2047) >> 5;       // first 32-row chunk of this tile
#pragma unroll
      for (int g = 0; g < 4; ++g)
        cs[((size_t)b * NCHUNK + c0 + g) * DMODEL + bn + tid] = colpart[g][tid];
    }
  }
}

// ---------------------------------------------------------------- fused scan + windowed average
// One thread per (b, chunk, d): reconstructs lead = P[i] and trail = P[i-w]
// from 32-row chunk sums + a <=31-row pre-walk, emits bf16 window averages
// directly from bf16 v (fp32 accumulation). 768 blocks -> ~12 waves/CU.
// All branches wave-uniform (64 consecutive d lie within half a head).
__global__ void winavg_fused(const u16* __restrict__ v, const float* __restrict__ cs,
                             u16* __restrict__ A2) {
  int t = blockIdx.x * blockDim.x + threadIdx.x;   // NBATCH*NCHUNK*DMODEL = 196608
  int d = t % DMODEL;
  int c = (t / DMODEL) % NCHUNK;
  int b = t / (DMODEL * NCHUNK);
  const int h = d >> 7;
  const int w = (2 << h) - 1;                      // 2^(h+1)-1
  const u16* vb = v + (size_t)b * S_LEN * DMODEL + d;       // row i at vb[i*DMODEL]
  const float* csb = cs + (size_t)b * NCHUNK * DMODEL + d;  // chunk cc at csb[cc*DMODEL]

  // lead = P[i0-1]
  const int i0 = c * CHUNK;
  float lead = 0.f;
  for (int cc = 0; cc < c; ++cc) lead += csb[(size_t)cc * DMODEL];

  // trail = P[i0-w-1]  (0 if window start precedes the sequence)
  float trail = 0.f;
  const int tstart = i0 - w;
  if (tstart > 0) {
    const int tc = tstart >> 5;                    // whole chunks before tstart
    for (int cc = 0; cc < tc; ++cc) trail += csb[(size_t)cc * DMODEL];
#pragma unroll 4
    for (int r = tc * CHUNK; r < tstart; ++r) trail += bf2f(vb[(size_t)r * DMODEL]);
  }

  u16* out = A2 + ((size_t)(b * S_LEN + i0)) * DMODEL + d;
#pragma unroll 4
  for (int r = 0; r < CHUNK; ++r) {
    const int i = i0 + r;
    lead += bf2f(vb[(size_t)i * DMODEL]);
    float o;
    if (i < w) {                                   // window not yet full (wave-uniform)
      o = lead / (float)(i + 1);
    } else {
      trail += bf2f(vb[(size_t)(i - w) * DMODEL]);
      o = (lead - trail) / (float)w;
    }
    out[(size_t)r * DMODEL] = f2bf(o);
  }
}

// ---------------------------------------------------------------- analytic attn_weights [B,H,S,S]
__global__ void attn_weights_kernel(float4* __restrict__ out4) {
  int t = blockIdx.x * blockDim.x + threadIdx.x;   // B*H*S*S/4
  int j0 = (t & 511) << 2;
  int i  = (t >> 9) & (S_LEN - 1);
  int bh = t >> 20;                                // S*S/4 = 2^20
  int h  = bh >= NHEADS ? bh - NHEADS : bh;
  int w  = (2 << h) - 1;
  int len = min(i + 1, w);
  float inv = 1.0f / (float)len;
  int lo = i - w + 1;
  float4 r;
  r.x = (j0     <= i && j0     >= lo) ? inv : 0.f;
  r.y = (j0 + 1 <= i && j0 + 1 >= lo) ? inv : 0.f;
  r.z = (j0 + 2 <= i && j0 + 2 >= lo) ? inv : 0.f;
  r.w = (j0 + 3 <= i && j0 + 3 >= lo) ? inv : 0.f;
  out4[t] = r;
}

// ---------------------------------------------------------------- launch
extern "C" void kernel_launch(void* const* d_in, const int* in_sizes, int n_in,
                              void* d_out, int out_size, void* d_ws, size_t ws_size,
                              hipStream_t stream) {
  const float* hidden = (const float*)d_in[0];
  const float* W_fc   = (const float*)d_in[1];
  const float* b_fc   = (const float*)d_in[2];
  const float* W_proj = (const float*)d_in[3];
  const float* b_proj = (const float*)d_in[4];
  float* outp = (float*)d_out;

  // workspace layout (bytes), total 35.4 MB:
  //   0        : A16   (12,582,912)  hidden bf16, later reused as winavg-output bf16
  //   12582912 : Wfc16 ( 4,718,592)
  //   17301504 : Wpj16 ( 4,718,592)
  //   22020096 : v16   (12,582,912)  bf16 v from GEMM1
  //   34603008 : csums (   786,432)  [B, NCHUNK, D] fp32 32-row chunk sums
  char* ws = (char*)d_ws;
  u16*   A16   = (u16*)(ws);
  u16*   Wfc16 = (u16*)(ws + 12582912);
  u16*   Wpj16 = (u16*)(ws + 17301504);
  u16*   v16   = (u16*)(ws + 22020096);
  float* csums = (float*)(ws + 34603008);

  // 1) all fp32->bf16 conversions in one launch
  cvt_all<<<10752, 256, 0, stream>>>((const float4*)hidden, (const float4*)W_fc,
                                     (const float4*)W_proj, (ushort4*)A16,
                                     (ushort4*)Wfc16, (ushort4*)Wpj16);

  // 2) GEMM1: v = hidden @ W_fc^T + b_fc -> bf16, fused 32-row chunk column sums (fp32)
  gemm_bt_bias<true, u16><<<dim3(DMODEL / 128, MROWS / 128), 256, 0, stream>>>(
      A16, Wfc16, b_fc, v16, csums, DMODEL, DMODEL);

  // 3) fused scan + windowed average -> bf16 (reuse A16 buffer)
  winavg_fused<<<(NBATCH * NCHUNK * DMODEL) / 256, 256, 0, stream>>>(v16, csums, A16);

  // 4) GEMM2: out = winavg @ W_proj^T + b_proj -> d_out[0 : B*S*D] fp32
  gemm_bt_bias<false, float><<<dim3(DMODEL / 128, MROWS / 128), 256, 0, stream>>>(
      A16, Wpj16, b_proj, outp, nullptr, DMODEL, DMODEL);

  // 5) attn_weights -> d_out[B*S*D : ...]
  attn_weights_kernel<<<(NBATCH * NHEADS * S_LEN * S_LEN / 4) / 256, 256, 0, stream>>>(
      (float4*)(outp + (size_t)MROWS * DMODEL));
}